// Round 25
// baseline (114.138 us; speedup 1.0000x reference)
//
#include <hip/hip_runtime.h>
#include <hip/hip_bf16.h>

// ---------------------------------------------------------------------------
// CompGCN layer:
//   fused prep (xcast + wpack + hist); coarse-bucket counting sort (low
//   write amp, 512-thread rank); per-bucket LDS fine sort (512 threads);
//   8-lane-group aggregation (8 keys/wave, 4 gather chains per lane);
//   persistent-block bf16-MFMA fused GEMM (1 block/CU, zero-barrier loop);
//   BN reduce stage1 + fused {stats finalize + BN apply + ReLU + rel GEMM}.
// ---------------------------------------------------------------------------

#define SCAN_BLOCK 256
#define CB 128               // keys per coarse bucket
#define CHUNK 4096           // edges per hist/rank block
#define NBC_MAX 800          // >= ceil(2V/CB) = 782
#define CAP 3072             // LDS staging cap per bucket (lambda=1024, 64 sigma)
#define RED1 64              // stage-1 reduce blocks (fixed)
#define NGB 128              // GEMM row-group blocks per column half

typedef __attribute__((ext_vector_type(8))) short short8v;   // 8 bf16
typedef __attribute__((ext_vector_type(4))) float float4v;   // MFMA C/D

__device__ inline short f2bf(float f) {
    union { float f; unsigned u; } c; c.f = f;
    unsigned u = c.u;
    return (short)((u + 0x7fffu + ((u >> 16) & 1u)) >> 16);  // RNE
}
__device__ inline unsigned packbf(float a, float b) {
    return (unsigned)(unsigned short)f2bf(a) |
           ((unsigned)(unsigned short)f2bf(b) << 16);
}
__device__ inline float bflo(unsigned u) { return __uint_as_float(u << 16); }
__device__ inline float bfhi(unsigned u) { return __uint_as_float(u & 0xffff0000u); }

// fused prep: blocks [0,XB) cast x/rel to bf16; [XB,XB+24) pack weights;
// [XB+24, XB+24+NBLK) per-block LDS histogram. All three are independent.
__global__ __launch_bounds__(256) void prep_kernel(
    const float* __restrict__ x, const float* __restrict__ rel,
    short* __restrict__ xbf, short* __restrict__ relbf,
    const float* __restrict__ in_w,
    const float* __restrict__ out_w,
    const float* __restrict__ loop_w,
    const float* __restrict__ loop_rel,
    short* __restrict__ wpack,
    const int* __restrict__ dst, int* __restrict__ counts,
    int V, int R, int E, int NBC, int XB)
{
    int b = blockIdx.x;
    if (b < XB) {
        // --- xcast ---
        size_t i = ((size_t)b * 256 + threadIdx.x) * 8;
        size_t nx = (size_t)V * 128;
        size_t total = nx + (size_t)R * 128;
        if (i >= total) return;
        const float* sp; short* dp; size_t k;
        if (i < nx) { sp = x; dp = xbf; k = i; }
        else        { sp = rel; dp = relbf; k = i - nx; }
        float4 v0 = *reinterpret_cast<const float4*>(sp + k);
        float4 v1 = *reinterpret_cast<const float4*>(sp + k + 4);
        short8v o;
        o[0] = f2bf(v0.x); o[1] = f2bf(v0.y); o[2] = f2bf(v0.z); o[3] = f2bf(v0.w);
        o[4] = f2bf(v1.x); o[5] = f2bf(v1.y); o[6] = f2bf(v1.z); o[7] = f2bf(v1.w);
        *reinterpret_cast<short8v*>(dp + k) = o;
    } else if (b < XB + 24) {
        // --- wpack ---
        int idx = (b - XB) * 256 + threadIdx.x;
        if (idx >= 3 * 8 * 4 * 64) return;
        int lane = idx & 63;
        int t    = (idx >> 6) & 3;
        int cblk = (idx >> 8) & 7;
        int m    = idx >> 11;
        const float* W = (m == 0) ? in_w : (m == 1) ? out_w : loop_w;
        int col = cblk * 16 + (lane & 15);
        int kb  = t * 32 + ((lane >> 4) << 3);
        short8v v;
#pragma unroll
        for (int j = 0; j < 8; ++j) {
            float w = W[(kb + j) * 128 + col];
            if (m == 2) w *= loop_rel[kb + j];
            v[j] = f2bf(w);
        }
        *reinterpret_cast<short8v*>(wpack + (size_t)idx * 8) = v;
    } else {
        // --- hist_coarse ---
        __shared__ int lh[NBC_MAX];
        int hb = b - XB - 24;
        for (int i = threadIdx.x; i < NBC; i += 256) lh[i] = 0;
        __syncthreads();
        int half = E >> 1;
        int e0 = hb * CHUNK;
        for (int i = 0; i < CHUNK / 256; ++i) {
            int e = e0 + i * 256 + threadIdx.x;
            if (e < E) {
                int key = dst[e] + (e < half ? 0 : V);
                atomicAdd(&lh[key >> 7], 1);
            }
        }
        __syncthreads();
        for (int i = threadIdx.x; i < NBC; i += 256)
            counts[(size_t)hb * NBC + i] = lh[i];
    }
}

// scan phase 1, TRANSPOSED read: logical l = bucket*NBLK + blk.
__global__ __launch_bounds__(SCAN_BLOCK) void scan_partial_t_kernel(
    const int* __restrict__ cnt_bm, int* __restrict__ partials,
    int CN, int NBC, int NBLK)
{
    __shared__ int red[SCAN_BLOCK];
    int l = blockIdx.x * SCAN_BLOCK + threadIdx.x;
    int v = 0;
    if (l < CN) {
        int bu = l / NBLK, bl = l - bu * NBLK;
        v = cnt_bm[(size_t)bl * NBC + bu];
    }
    red[threadIdx.x] = v;
    __syncthreads();
    for (int s = SCAN_BLOCK / 2; s > 0; s >>= 1) {
        if (threadIdx.x < s) red[threadIdx.x] += red[threadIdx.x + s];
        __syncthreads();
    }
    if (threadIdx.x == 0) partials[blockIdx.x] = red[0];
}

// scan phase 2: block bid reduces partials[0..bid) itself, then local scan.
__global__ __launch_bounds__(SCAN_BLOCK) void scan_final_t_kernel(
    const int* __restrict__ cnt_bm, const int* __restrict__ partials,
    int* __restrict__ base, int CN, int NBC, int NBLK)
{
    __shared__ int sh[SCAN_BLOCK];
    __shared__ int pref_s;
    int t = threadIdx.x;
    int bid = blockIdx.x;

    int acc = 0;
    for (int i = t; i < bid; i += SCAN_BLOCK) acc += partials[i];
    sh[t] = acc;
    __syncthreads();
    for (int s = SCAN_BLOCK / 2; s > 0; s >>= 1) {
        if (t < s) sh[t] += sh[t + s];
        __syncthreads();
    }
    if (t == 0) pref_s = sh[0];
    __syncthreads();
    int pref = pref_s;
    __syncthreads();   // sh[] reuse

    int l = bid * SCAN_BLOCK + t;
    int v = 0;
    if (l < CN) {
        int bu = l / NBLK, bl = l - bu * NBLK;
        v = cnt_bm[(size_t)bl * NBC + bu];
    }
    sh[t] = v;
    __syncthreads();
    for (int s = 1; s < SCAN_BLOCK; s <<= 1) {
        int u = (t >= s) ? sh[t - s] : 0;
        __syncthreads();
        sh[t] += u;
        __syncthreads();
    }
    if (l < CN) base[l] = pref + sh[t] - v;
}

// scatter payload; per-(bucket,block) runs contiguous, written from one CU.
// payload: (src<<16 | type<<8 | key&127, norm-bits). 512 threads.
__global__ __launch_bounds__(512) void rank_coarse_kernel(
    const int* __restrict__ dst,
    const int* __restrict__ src,
    const int* __restrict__ edge_type,
    const float* __restrict__ edge_norm,
    const int* __restrict__ base,
    uint2* __restrict__ pay,
    int E, int V, int NBC, int NBLK)
{
    __shared__ int lh[NBC_MAX];
    __shared__ int lb[NBC_MAX];
    for (int i = threadIdx.x; i < NBC; i += 512) {
        lh[i] = 0;
        lb[i] = base[(size_t)i * NBLK + blockIdx.x];
    }
    __syncthreads();
    int half = E >> 1;
    int e0 = blockIdx.x * CHUNK;
    for (int i = 0; i < CHUNK / 512; ++i) {
        int e = e0 + i * 512 + threadIdx.x;
        if (e < E) {
            int d = dst[e], s = src[e], t = edge_type[e];
            float n = edge_norm[e];
            int key = d + (e < half ? 0 : V);
            int b = key >> 7;
            int r = atomicAdd(&lh[b], 1);
            pay[lb[b] + r] = make_uint2(
                ((unsigned)s << 16) | ((unsigned)t << 8) | (unsigned)(key & 127),
                __float_as_uint(n));
        }
    }
}

// one block per coarse bucket: LDS counting sort of the bucket's payload;
// writes key-sorted pay2 (coalesced) + per-key CSR foffg [NK+1]. 512 threads.
__global__ __launch_bounds__(512) void fine_sort_kernel(
    const uint2* __restrict__ pay,
    const int* __restrict__ base,
    uint2* __restrict__ pay2,
    int* __restrict__ foffg,
    int E, int NK, int NBC, int NBLK)
{
    __shared__ uint2 pay_s[CAP];     // 24 KB
    __shared__ int fcnt[CB];
    __shared__ int ssc[CB];
    __shared__ int fcur[CB];

    int b = blockIdx.x;
    int beg = base[(size_t)b * NBLK];
    int end = (b + 1 < NBC) ? base[(size_t)(b + 1) * NBLK] : E;
    int cnt = end - beg;
    int tid = threadIdx.x;

    if (tid < CB) fcnt[tid] = 0;
    __syncthreads();
    for (int j = tid; j < cnt; j += 512)
        atomicAdd(&fcnt[pay[beg + j].x & 127u], 1);
    __syncthreads();
    if (tid < CB) ssc[tid] = fcnt[tid];
    __syncthreads();
    for (int s = 1; s < CB; s <<= 1) {
        int v = 0;
        if (tid < CB && tid >= s) v = ssc[tid - s];
        __syncthreads();
        if (tid < CB) ssc[tid] += v;
        __syncthreads();
    }
    if (tid < CB) {
        int ex = ssc[tid] - fcnt[tid];
        fcur[tid] = ex;
        int key = b * CB + tid;
        if (key <= NK) foffg[key] = beg + ex;
    }
    __syncthreads();

    if (cnt <= CAP) {
        for (int j = tid; j < cnt; j += 512) {
            uint2 p = pay[beg + j];
            int r = atomicAdd(&fcur[p.x & 127u], 1);
            pay_s[r] = p;
        }
        __syncthreads();
        for (int j = tid; j < cnt; j += 512) pay2[beg + j] = pay_s[j];
    } else {
        for (int j = tid; j < cnt; j += 512) {
            uint2 p = pay[beg + j];
            int r = atomicAdd(&fcur[p.x & 127u], 1);
            pay2[beg + r] = p;
        }
    }
}

// 8-lane group per key (8 keys/wave): 4 independent gather chains per lane
// (2 x uint4 per row pair), 32B per lane, branch-free tail predication.
__global__ __launch_bounds__(256) void aggregate_g8_kernel(
    const short* __restrict__ xbf,
    const short* __restrict__ relbf,
    const uint2* __restrict__ pay2,
    const int* __restrict__ foffg,
    short* __restrict__ accbf,       // [NK,128]
    int NK, int E)
{
    int wid = (blockIdx.x * 256 + threadIdx.x) >> 6;
    int lane = threadIdx.x & 63;
    int g = lane >> 3;               // group 0..7
    int sub = lane & 7;
    int k = wid * 8 + g;
    if (k >= NK) k = NK - 1;         // safety (duplicate writes identical)
    int f0 = sub << 4;               // 16 bf16 features per lane

    int beg = foffg[k];
    int end = foffg[k + 1];
    int cnt = end - beg;

    // wave-max degree across the 8 groups
    int maxc = cnt;
    maxc = max(maxc, __shfl_xor(maxc, 8, 64));
    maxc = max(maxc, __shfl_xor(maxc, 16, 64));
    maxc = max(maxc, __shfl_xor(maxc, 32, 64));

    float a0 = 0.f, a1 = 0.f, a2 = 0.f, a3 = 0.f;
    float a4 = 0.f, a5 = 0.f, a6 = 0.f, a7 = 0.f;
    float a8 = 0.f, a9 = 0.f, aA = 0.f, aB = 0.f;
    float aC = 0.f, aD = 0.f, aE = 0.f, aF = 0.f;

    for (int bas = 0; bas < maxc; bas += 8) {
        // batch load: 8 edges per group (clamped to valid addresses)
        int off = bas + sub;
        int cidx = (cnt > 0) ? min(off, cnt - 1) : 0;
        int j = min(beg + cidx, E - 1);
        uint2 p = pay2[j];
        int qmax = min(8, maxc - bas);
        for (int q = 0; q < qmax; ++q) {
            int srcl = (lane & 56) + q;          // per-group broadcast source
            unsigned pqx = __shfl(p.x, srcl, 64);
            unsigned pqn = __shfl(p.y, srcl, 64);
            float n = ((bas + q) < cnt) ? __uint_as_float(pqn) : 0.f;
            int s = (int)(pqx >> 16);
            int t = (int)((pqx >> 8) & 0xffu);
            const short* xr = xbf + (size_t)s * 128 + f0;
            const short* rr = relbf + (size_t)t * 128 + f0;
            uint4 xv0 = *reinterpret_cast<const uint4*>(xr);
            uint4 xv1 = *reinterpret_cast<const uint4*>(xr + 8);
            uint4 rv0 = *reinterpret_cast<const uint4*>(rr);
            uint4 rv1 = *reinterpret_cast<const uint4*>(rr + 8);
            a0 += bflo(xv0.x) * bflo(rv0.x) * n;
            a1 += bfhi(xv0.x) * bfhi(rv0.x) * n;
            a2 += bflo(xv0.y) * bflo(rv0.y) * n;
            a3 += bfhi(xv0.y) * bfhi(rv0.y) * n;
            a4 += bflo(xv0.z) * bflo(rv0.z) * n;
            a5 += bfhi(xv0.z) * bfhi(rv0.z) * n;
            a6 += bflo(xv0.w) * bflo(rv0.w) * n;
            a7 += bfhi(xv0.w) * bfhi(rv0.w) * n;
            a8 += bflo(xv1.x) * bflo(rv1.x) * n;
            a9 += bfhi(xv1.x) * bfhi(rv1.x) * n;
            aA += bflo(xv1.y) * bflo(rv1.y) * n;
            aB += bfhi(xv1.y) * bfhi(rv1.y) * n;
            aC += bflo(xv1.z) * bflo(rv1.z) * n;
            aD += bfhi(xv1.z) * bfhi(rv1.z) * n;
            aE += bflo(xv1.w) * bflo(rv1.w) * n;
            aF += bfhi(xv1.w) * bfhi(rv1.w) * n;
        }
    }
    uint4 o0, o1;
    o0.x = packbf(a0, a1); o0.y = packbf(a2, a3);
    o0.z = packbf(a4, a5); o0.w = packbf(a6, a7);
    o1.x = packbf(a8, a9); o1.y = packbf(aA, aB);
    o1.z = packbf(aC, aD); o1.w = packbf(aE, aF);
    *reinterpret_cast<uint4*>(accbf + (size_t)k * 128 + f0) = o0;
    *reinterpret_cast<uint4*>(accbf + (size_t)k * 128 + f0 + 8) = o1;
}

// bf16 MFMA fused GEMM + bias + /3; persistent blocks (1/CU):
// 48KB weights staged ONCE, zero-barrier tile loop.
__global__ __launch_bounds__(512) void fused_gemm_mfma_kernel(
    const short* __restrict__ accbf,     // [2V,128]
    const short* __restrict__ xbf,       // [V,128]
    const short* __restrict__ wpack,
    const float* __restrict__ bias,
    short* __restrict__ hbf,             // [V,128] bf16 intermediate
    float* __restrict__ stats_part,      // [NGB][256]
    int V, int NRB)
{
    __shared__ short wlds[3 * 4 * 4 * 64 * 8];   // 48 KB
    __shared__ float s_red[128];                 // [0:64] sum, [64:128] sumsq

    int tid  = threadIdx.x;
    int wave = tid >> 6;
    int lane = tid & 63;
    int kgrp = lane >> 4;
    int r16  = lane & 15;
    int bid  = blockIdx.x >> 1;
    int hh   = blockIdx.x & 1;

    if (tid < 128) s_red[tid] = 0.f;

    {
        const short8v* wsv = reinterpret_cast<const short8v*>(wpack);
        short8v* wldv = reinterpret_cast<short8v*>(wlds);
#pragma unroll
        for (int i = 0; i < 6; ++i) {
            int idx = i * 512 + tid;
            int l  = idx & 63;
            int t  = (idx >> 6) & 3;
            int cb = (idx >> 8) & 3;
            int m  = idx >> 10;
            wldv[idx] = wsv[(((size_t)m * 8 + (4 * hh + cb)) * 4 + t) * 64 + l];
        }
    }
    __syncthreads();   // weights staged; s_red zeroed. NO barriers after this.

    const short8v* wldv = reinterpret_cast<const short8v*>(wlds);
    float ps[4] = {0.f, 0.f, 0.f, 0.f};
    float pq[4] = {0.f, 0.f, 0.f, 0.f};

    for (int rt = bid; rt < NRB; rt += NGB) {
        int row0 = rt * 128 + wave * 16;
        int rowl = row0 + r16;
        int rowc = min(rowl, V - 1);

        short8v af[3][4];
        {
            const short* A0 = accbf + (size_t)rowc * 128;
            const short* A1 = accbf + (size_t)(V + rowc) * 128;
            const short* A2 = xbf + (size_t)rowc * 128;
#pragma unroll
            for (int t = 0; t < 4; ++t) {
                int o = t * 32 + (kgrp << 3);
                af[0][t] = *reinterpret_cast<const short8v*>(A0 + o);
                af[1][t] = *reinterpret_cast<const short8v*>(A1 + o);
                af[2][t] = *reinterpret_cast<const short8v*>(A2 + o);
            }
        }

        float4v c[4];
#pragma unroll
        for (int b = 0; b < 4; ++b) c[b] = (float4v)(0.f);

#pragma unroll
        for (int m = 0; m < 3; ++m)
#pragma unroll
            for (int t = 0; t < 4; ++t) {
#pragma unroll
                for (int b = 0; b < 4; ++b) {
                    short8v bf_ = wldv[(((m * 4 + b) * 4) + t) * 64 + lane];
                    c[b] = __builtin_amdgcn_mfma_f32_16x16x32_bf16(af[m][t], bf_, c[b], 0, 0, 0);
                }
            }

        // epilogue: C/D layout col=lane&15, row=(lane>>4)*4+r  [m89]
#pragma unroll
        for (int b = 0; b < 4; ++b) {
            int col = hh * 64 + b * 16 + r16;
            float bv = bias[col];
#pragma unroll
            for (int r = 0; r < 4; ++r) {
                int row = row0 + kgrp * 4 + r;
                if (row < V) {
                    float v = c[b][r] * (1.f / 3.f) + bv;
                    hbf[(size_t)row * 128 + col] = f2bf(v);
                    ps[b] += v;
                    pq[b] += v * v;
                }
            }
        }
    }

#pragma unroll
    for (int b = 0; b < 4; ++b) {
        int cl = b * 16 + r16;
        atomicAdd(&s_red[cl], ps[b]);
        atomicAdd(&s_red[64 + cl], pq[b]);
    }
    __syncthreads();
    if (tid < 64)
        stats_part[(size_t)bid * 256 + hh * 64 + tid] = s_red[tid];
    else if (tid < 128)
        stats_part[(size_t)bid * 256 + 128 + hh * 64 + (tid - 64)] = s_red[tid];
}

// BN reduce stage 1: 64 blocks, each sums a strided subset of NB partials
__global__ __launch_bounds__(256) void bn_reduce1_kernel(
    const float* __restrict__ stats_part, float* __restrict__ stage, int NB)
{
    int col = threadIdx.x;
    float s = 0.f;
    for (int i = blockIdx.x; i < NB; i += RED1)
        s += stats_part[(size_t)i * 256 + col];
    stage[(size_t)blockIdx.x * 256 + col] = s;
}

// fused: per-block stats finalize + BN apply + ReLU (bf16 in, f32 out);
// blocks >= NBA compute out_rel = rel @ w_rel.
__global__ __launch_bounds__(256) void bn_apply_fused_kernel(
    const short* __restrict__ hbf,
    float* __restrict__ hout,
    const float* __restrict__ stage,
    const float* __restrict__ gamma,
    const float* __restrict__ beta,
    int V, int NBA,
    const float* __restrict__ rel,
    const float* __restrict__ w_rel,
    float* __restrict__ out_rel,
    int R)
{
    int tid = threadIdx.x;
    if ((int)blockIdx.x >= NBA) {
        int rb = blockIdx.x - NBA;
        int col = tid & 127;
        int row = rb * 2 + (tid >> 7);
        if (row >= R) return;
        float acc = 0.f;
        for (int k = 0; k < 128; ++k)
            acc += rel[row * 128 + k] * w_rel[k * 128 + col];
        out_rel[row * 128 + col] = acc;
        return;
    }

    __shared__ float st[256];
    {
        float s0 = 0.f, s1 = 0.f, s2 = 0.f, s3 = 0.f;
#pragma unroll
        for (int i = 0; i < RED1; i += 4) {
            s0 += stage[(size_t)(i + 0) * 256 + tid];
            s1 += stage[(size_t)(i + 1) * 256 + tid];
            s2 += stage[(size_t)(i + 2) * 256 + tid];
            s3 += stage[(size_t)(i + 3) * 256 + tid];
        }
        st[tid] = (s0 + s1) + (s2 + s3);
    }
    __syncthreads();

    int c4   = (tid & 31) << 2;
    int rsub = tid >> 5;
    float inv_v = 1.f / (float)V;
    float sc[4], sh[4];
#pragma unroll
    for (int j = 0; j < 4; ++j) {
        int col = c4 + j;
        float mean = st[col] * inv_v;
        float var  = st[128 + col] * inv_v - mean * mean;
        float s = rsqrtf(var + 1e-5f) * gamma[col];
        sc[j] = s;
        sh[j] = beta[col] - mean * s;
    }
    for (int row = blockIdx.x * 8 + rsub; row < V; row += NBA * 8) {
        uint2 u = *reinterpret_cast<const uint2*>(hbf + (size_t)row * 128 + c4);
        float4 v;
        v.x = fmaxf(bflo(u.x) * sc[0] + sh[0], 0.f);
        v.y = fmaxf(bfhi(u.x) * sc[1] + sh[1], 0.f);
        v.z = fmaxf(bflo(u.y) * sc[2] + sh[2], 0.f);
        v.w = fmaxf(bfhi(u.y) * sc[3] + sh[3], 0.f);
        *reinterpret_cast<float4*>(hout + (size_t)row * 128 + c4) = v;
    }
}

extern "C" void kernel_launch(void* const* d_in, const int* in_sizes, int n_in,
                              void* d_out, int out_size, void* d_ws, size_t ws_size,
                              hipStream_t stream)
{
    const float* x         = (const float*)d_in[0];
    const float* rel_repr  = (const float*)d_in[1];
    const float* edge_norm = (const float*)d_in[2];
    const float* in_w      = (const float*)d_in[3];
    const float* out_w     = (const float*)d_in[4];
    const float* loop_w    = (const float*)d_in[5];
    const float* w_rel     = (const float*)d_in[6];
    const float* loop_rel  = (const float*)d_in[7];
    const float* bias      = (const float*)d_in[8];
    const float* bn_gamma  = (const float*)d_in[9];
    const float* bn_beta   = (const float*)d_in[10];
    const int* edge_type   = (const int*)d_in[11];
    const int* src         = (const int*)d_in[12];
    const int* dst         = (const int*)d_in[13];

    const int V = in_sizes[0] / 128;     // 50000
    const int E = in_sizes[2];           // 800000
    const int R = in_sizes[1] / 128;     // 200
    const int NK = 2 * V;                // keys: [dst(in) ; dst(out)]
    const int NBC = (NK + CB - 1) / CB;              // coarse buckets (782)
    const int NBLK = (E + CHUNK - 1) / CHUNK;        // hist/rank blocks (196)
    const int CN = NBC * NBLK;                       // scan length
    const int NB2 = (CN + SCAN_BLOCK - 1) / SCAN_BLOCK;
    const int NRB = (V + 127) / 128;                 // GEMM row tiles (391)
    const int NBA = 256;                             // bn_apply blocks
    const int XB  = (int)((((size_t)(V + R) * 128) / 8 + 255) / 256);  // xcast blocks

    float* hout    = (float*)d_out;              // [V,128]
    float* out_rel = hout + (size_t)V * 128;     // [R,128]

    // workspace layout
    char* wp_ = (char*)d_ws;
    short* accbf    = (short*)wp_;  wp_ += (size_t)NK * 128 * sizeof(short);
    short* xbf      = (short*)wp_;  wp_ += (size_t)V * 128 * sizeof(short);
    short* relbf    = (short*)wp_;  wp_ += (size_t)R * 128 * sizeof(short);
    short* hbf      = (short*)wp_;  wp_ += (size_t)V * 128 * sizeof(short);
    short* wpack    = (short*)wp_;  wp_ += (size_t)3 * 8 * 4 * 64 * 8 * sizeof(short);
    float* stats_pt = (float*)wp_;  wp_ += (size_t)NGB * 256 * sizeof(float);
    float* stage    = (float*)wp_;  wp_ += (size_t)RED1 * 256 * sizeof(float);
    int*   counts   = (int*)wp_;    wp_ += (size_t)CN * sizeof(int);   // block-major
    int*   basep    = (int*)wp_;    wp_ += (size_t)CN * sizeof(int);   // bucket-major
    int*   partials = (int*)wp_;    wp_ += 1024 * sizeof(int);
    int*   foffg    = (int*)wp_;    wp_ += ((size_t)NK + 2) * sizeof(int);
    wp_ = (char*)(((uintptr_t)wp_ + 15) & ~(uintptr_t)15);
    uint2* pay      = (uint2*)wp_;  wp_ += (size_t)E * sizeof(uint2);
    uint2* pay2     = (uint2*)wp_;

    // NOTE: no memset needed — every consumed workspace buffer is fully
    // written each call.

    prep_kernel<<<XB + 24 + NBLK, 256, 0, stream>>>(
        x, rel_repr, xbf, relbf,
        in_w, out_w, loop_w, loop_rel, wpack,
        dst, counts, V, R, E, NBC, XB);

    scan_partial_t_kernel<<<NB2, SCAN_BLOCK, 0, stream>>>(counts, partials, CN, NBC, NBLK);
    scan_final_t_kernel<<<NB2, SCAN_BLOCK, 0, stream>>>(counts, partials, basep, CN, NBC, NBLK);
    rank_coarse_kernel<<<NBLK, 512, 0, stream>>>(
        dst, src, edge_type, edge_norm, basep, pay, E, V, NBC, NBLK);
    fine_sort_kernel<<<NBC, 512, 0, stream>>>(
        pay, basep, pay2, foffg, E, NK, NBC, NBLK);

    {
        int waves = (NK + 7) / 8;                        // 12500
        int blocks = (waves * 64 + 255) / 256;           // 3125
        aggregate_g8_kernel<<<blocks, 256, 0, stream>>>(
            xbf, relbf, pay2, foffg, accbf, NK, E);
    }

    fused_gemm_mfma_kernel<<<NGB * 2, 512, 0, stream>>>(
        accbf, xbf, wpack, bias, hbf, stats_pt, V, NRB);

    bn_reduce1_kernel<<<RED1, 256, 0, stream>>>(stats_pt, stage, NGB);
    bn_apply_fused_kernel<<<NBA + (R + 1) / 2, 256, 0, stream>>>(
        hbf, hout, stage, bn_gamma, bn_beta, V, NBA,
        rel_repr, w_rel, out_rel, R);
}

// Round 26
// 111.945 us; speedup vs baseline: 1.0196x; 1.0196x over previous
//
#include <hip/hip_runtime.h>
#include <hip/hip_bf16.h>

// ---------------------------------------------------------------------------
// CompGCN layer (round-24 best configuration, g16 aggregate restored):
//   fused prep (xcast + wpack + hist); coarse-bucket counting sort (low
//   write amp, 512-thread rank); per-bucket LDS fine sort (512 threads);
//   16-lane-group aggregation (4 keys/wave, 4 edge-chains in flight);
//   persistent-block bf16-MFMA fused GEMM (1 block/CU, zero-barrier loop);
//   BN reduce stage1 + fused {stats finalize + BN apply + ReLU + rel GEMM}.
// ---------------------------------------------------------------------------

#define SCAN_BLOCK 256
#define CB 128               // keys per coarse bucket
#define CHUNK 4096           // edges per hist/rank block
#define NBC_MAX 800          // >= ceil(2V/CB) = 782
#define CAP 3072             // LDS staging cap per bucket (lambda=1024, 64 sigma)
#define RED1 64              // stage-1 reduce blocks (fixed)
#define NGB 128              // GEMM row-group blocks per column half

typedef __attribute__((ext_vector_type(8))) short short8v;   // 8 bf16
typedef __attribute__((ext_vector_type(4))) float float4v;   // MFMA C/D

__device__ inline short f2bf(float f) {
    union { float f; unsigned u; } c; c.f = f;
    unsigned u = c.u;
    return (short)((u + 0x7fffu + ((u >> 16) & 1u)) >> 16);  // RNE
}
__device__ inline unsigned packbf(float a, float b) {
    return (unsigned)(unsigned short)f2bf(a) |
           ((unsigned)(unsigned short)f2bf(b) << 16);
}
__device__ inline float bflo(unsigned u) { return __uint_as_float(u << 16); }
__device__ inline float bfhi(unsigned u) { return __uint_as_float(u & 0xffff0000u); }

// fused prep: blocks [0,XB) cast x/rel to bf16; [XB,XB+24) pack weights;
// [XB+24, XB+24+NBLK) per-block LDS histogram. All three are independent.
__global__ __launch_bounds__(256) void prep_kernel(
    const float* __restrict__ x, const float* __restrict__ rel,
    short* __restrict__ xbf, short* __restrict__ relbf,
    const float* __restrict__ in_w,
    const float* __restrict__ out_w,
    const float* __restrict__ loop_w,
    const float* __restrict__ loop_rel,
    short* __restrict__ wpack,
    const int* __restrict__ dst, int* __restrict__ counts,
    int V, int R, int E, int NBC, int XB)
{
    int b = blockIdx.x;
    if (b < XB) {
        // --- xcast ---
        size_t i = ((size_t)b * 256 + threadIdx.x) * 8;
        size_t nx = (size_t)V * 128;
        size_t total = nx + (size_t)R * 128;
        if (i >= total) return;
        const float* sp; short* dp; size_t k;
        if (i < nx) { sp = x; dp = xbf; k = i; }
        else        { sp = rel; dp = relbf; k = i - nx; }
        float4 v0 = *reinterpret_cast<const float4*>(sp + k);
        float4 v1 = *reinterpret_cast<const float4*>(sp + k + 4);
        short8v o;
        o[0] = f2bf(v0.x); o[1] = f2bf(v0.y); o[2] = f2bf(v0.z); o[3] = f2bf(v0.w);
        o[4] = f2bf(v1.x); o[5] = f2bf(v1.y); o[6] = f2bf(v1.z); o[7] = f2bf(v1.w);
        *reinterpret_cast<short8v*>(dp + k) = o;
    } else if (b < XB + 24) {
        // --- wpack ---
        int idx = (b - XB) * 256 + threadIdx.x;
        if (idx >= 3 * 8 * 4 * 64) return;
        int lane = idx & 63;
        int t    = (idx >> 6) & 3;
        int cblk = (idx >> 8) & 7;
        int m    = idx >> 11;
        const float* W = (m == 0) ? in_w : (m == 1) ? out_w : loop_w;
        int col = cblk * 16 + (lane & 15);
        int kb  = t * 32 + ((lane >> 4) << 3);
        short8v v;
#pragma unroll
        for (int j = 0; j < 8; ++j) {
            float w = W[(kb + j) * 128 + col];
            if (m == 2) w *= loop_rel[kb + j];
            v[j] = f2bf(w);
        }
        *reinterpret_cast<short8v*>(wpack + (size_t)idx * 8) = v;
    } else {
        // --- hist_coarse ---
        __shared__ int lh[NBC_MAX];
        int hb = b - XB - 24;
        for (int i = threadIdx.x; i < NBC; i += 256) lh[i] = 0;
        __syncthreads();
        int half = E >> 1;
        int e0 = hb * CHUNK;
        for (int i = 0; i < CHUNK / 256; ++i) {
            int e = e0 + i * 256 + threadIdx.x;
            if (e < E) {
                int key = dst[e] + (e < half ? 0 : V);
                atomicAdd(&lh[key >> 7], 1);
            }
        }
        __syncthreads();
        for (int i = threadIdx.x; i < NBC; i += 256)
            counts[(size_t)hb * NBC + i] = lh[i];
    }
}

// scan phase 1, TRANSPOSED read: logical l = bucket*NBLK + blk.
__global__ __launch_bounds__(SCAN_BLOCK) void scan_partial_t_kernel(
    const int* __restrict__ cnt_bm, int* __restrict__ partials,
    int CN, int NBC, int NBLK)
{
    __shared__ int red[SCAN_BLOCK];
    int l = blockIdx.x * SCAN_BLOCK + threadIdx.x;
    int v = 0;
    if (l < CN) {
        int bu = l / NBLK, bl = l - bu * NBLK;
        v = cnt_bm[(size_t)bl * NBC + bu];
    }
    red[threadIdx.x] = v;
    __syncthreads();
    for (int s = SCAN_BLOCK / 2; s > 0; s >>= 1) {
        if (threadIdx.x < s) red[threadIdx.x] += red[threadIdx.x + s];
        __syncthreads();
    }
    if (threadIdx.x == 0) partials[blockIdx.x] = red[0];
}

// scan phase 2: block bid reduces partials[0..bid) itself, then local scan.
__global__ __launch_bounds__(SCAN_BLOCK) void scan_final_t_kernel(
    const int* __restrict__ cnt_bm, const int* __restrict__ partials,
    int* __restrict__ base, int CN, int NBC, int NBLK)
{
    __shared__ int sh[SCAN_BLOCK];
    __shared__ int pref_s;
    int t = threadIdx.x;
    int bid = blockIdx.x;

    int acc = 0;
    for (int i = t; i < bid; i += SCAN_BLOCK) acc += partials[i];
    sh[t] = acc;
    __syncthreads();
    for (int s = SCAN_BLOCK / 2; s > 0; s >>= 1) {
        if (t < s) sh[t] += sh[t + s];
        __syncthreads();
    }
    if (t == 0) pref_s = sh[0];
    __syncthreads();
    int pref = pref_s;
    __syncthreads();   // sh[] reuse

    int l = bid * SCAN_BLOCK + t;
    int v = 0;
    if (l < CN) {
        int bu = l / NBLK, bl = l - bu * NBLK;
        v = cnt_bm[(size_t)bl * NBC + bu];
    }
    sh[t] = v;
    __syncthreads();
    for (int s = 1; s < SCAN_BLOCK; s <<= 1) {
        int u = (t >= s) ? sh[t - s] : 0;
        __syncthreads();
        sh[t] += u;
        __syncthreads();
    }
    if (l < CN) base[l] = pref + sh[t] - v;
}

// scatter payload; per-(bucket,block) runs contiguous, written from one CU.
// payload: (src<<16 | type<<8 | key&127, norm-bits). 512 threads.
__global__ __launch_bounds__(512) void rank_coarse_kernel(
    const int* __restrict__ dst,
    const int* __restrict__ src,
    const int* __restrict__ edge_type,
    const float* __restrict__ edge_norm,
    const int* __restrict__ base,
    uint2* __restrict__ pay,
    int E, int V, int NBC, int NBLK)
{
    __shared__ int lh[NBC_MAX];
    __shared__ int lb[NBC_MAX];
    for (int i = threadIdx.x; i < NBC; i += 512) {
        lh[i] = 0;
        lb[i] = base[(size_t)i * NBLK + blockIdx.x];
    }
    __syncthreads();
    int half = E >> 1;
    int e0 = blockIdx.x * CHUNK;
    for (int i = 0; i < CHUNK / 512; ++i) {
        int e = e0 + i * 512 + threadIdx.x;
        if (e < E) {
            int d = dst[e], s = src[e], t = edge_type[e];
            float n = edge_norm[e];
            int key = d + (e < half ? 0 : V);
            int b = key >> 7;
            int r = atomicAdd(&lh[b], 1);
            pay[lb[b] + r] = make_uint2(
                ((unsigned)s << 16) | ((unsigned)t << 8) | (unsigned)(key & 127),
                __float_as_uint(n));
        }
    }
}

// one block per coarse bucket: LDS counting sort of the bucket's payload;
// writes key-sorted pay2 (coalesced) + per-key CSR foffg [NK+1]. 512 threads.
__global__ __launch_bounds__(512) void fine_sort_kernel(
    const uint2* __restrict__ pay,
    const int* __restrict__ base,
    uint2* __restrict__ pay2,
    int* __restrict__ foffg,
    int E, int NK, int NBC, int NBLK)
{
    __shared__ uint2 pay_s[CAP];     // 24 KB
    __shared__ int fcnt[CB];
    __shared__ int ssc[CB];
    __shared__ int fcur[CB];

    int b = blockIdx.x;
    int beg = base[(size_t)b * NBLK];
    int end = (b + 1 < NBC) ? base[(size_t)(b + 1) * NBLK] : E;
    int cnt = end - beg;
    int tid = threadIdx.x;

    if (tid < CB) fcnt[tid] = 0;
    __syncthreads();
    for (int j = tid; j < cnt; j += 512)
        atomicAdd(&fcnt[pay[beg + j].x & 127u], 1);
    __syncthreads();
    if (tid < CB) ssc[tid] = fcnt[tid];
    __syncthreads();
    for (int s = 1; s < CB; s <<= 1) {
        int v = 0;
        if (tid < CB && tid >= s) v = ssc[tid - s];
        __syncthreads();
        if (tid < CB) ssc[tid] += v;
        __syncthreads();
    }
    if (tid < CB) {
        int ex = ssc[tid] - fcnt[tid];
        fcur[tid] = ex;
        int key = b * CB + tid;
        if (key <= NK) foffg[key] = beg + ex;
    }
    __syncthreads();

    if (cnt <= CAP) {
        for (int j = tid; j < cnt; j += 512) {
            uint2 p = pay[beg + j];
            int r = atomicAdd(&fcur[p.x & 127u], 1);
            pay_s[r] = p;
        }
        __syncthreads();
        for (int j = tid; j < cnt; j += 512) pay2[beg + j] = pay_s[j];
    } else {
        for (int j = tid; j < cnt; j += 512) {
            uint2 p = pay[beg + j];
            int r = atomicAdd(&fcur[p.x & 127u], 1);
            pay2[beg + r] = p;
        }
    }
}

// 16-lane group per key (4 keys/wave): 4 independent edge-gather chains per
// wave, 16B row loads (8 bf16/lane), branch-free tail predication.
__global__ __launch_bounds__(256) void aggregate_g16_kernel(
    const short* __restrict__ xbf,
    const short* __restrict__ relbf,
    const uint2* __restrict__ pay2,
    const int* __restrict__ foffg,
    short* __restrict__ accbf,       // [NK,128]
    int NK, int E)
{
    int wid = (blockIdx.x * 256 + threadIdx.x) >> 6;
    int lane = threadIdx.x & 63;
    int g = lane >> 4;
    int sub = lane & 15;
    int k = wid * 4 + g;
    if (k >= NK) k = NK - 1;
    int f0 = sub << 3;

    int beg = foffg[k];
    int end = foffg[k + 1];
    int cnt = end - beg;

    int maxc = cnt;
    maxc = max(maxc, __shfl_xor(maxc, 16, 64));
    maxc = max(maxc, __shfl_xor(maxc, 32, 64));

    float a0 = 0.f, a1 = 0.f, a2 = 0.f, a3 = 0.f;
    float a4 = 0.f, a5 = 0.f, a6 = 0.f, a7 = 0.f;

    for (int bas = 0; bas < maxc; bas += 16) {
        int off = bas + sub;
        int cidx = (cnt > 0) ? min(off, cnt - 1) : 0;
        int j = min(beg + cidx, E - 1);
        uint2 p = pay2[j];
        int qmax = min(16, maxc - bas);
        for (int q = 0; q < qmax; ++q) {
            int srcl = (lane & 48) + q;
            unsigned pqx = __shfl(p.x, srcl, 64);
            unsigned pqn = __shfl(p.y, srcl, 64);
            float n = ((bas + q) < cnt) ? __uint_as_float(pqn) : 0.f;
            int s = (int)(pqx >> 16);
            int t = (int)((pqx >> 8) & 0xffu);
            uint4 xv = *reinterpret_cast<const uint4*>(xbf + (size_t)s * 128 + f0);
            uint4 rv = *reinterpret_cast<const uint4*>(relbf + (size_t)t * 128 + f0);
            a0 += bflo(xv.x) * bflo(rv.x) * n;
            a1 += bfhi(xv.x) * bfhi(rv.x) * n;
            a2 += bflo(xv.y) * bflo(rv.y) * n;
            a3 += bfhi(xv.y) * bfhi(rv.y) * n;
            a4 += bflo(xv.z) * bflo(rv.z) * n;
            a5 += bfhi(xv.z) * bfhi(rv.z) * n;
            a6 += bflo(xv.w) * bflo(rv.w) * n;
            a7 += bfhi(xv.w) * bfhi(rv.w) * n;
        }
    }
    uint4 o;
    o.x = packbf(a0, a1);
    o.y = packbf(a2, a3);
    o.z = packbf(a4, a5);
    o.w = packbf(a6, a7);
    *reinterpret_cast<uint4*>(accbf + (size_t)k * 128 + f0) = o;
}

// bf16 MFMA fused GEMM + bias + /3; persistent blocks (1/CU):
// 48KB weights staged ONCE, zero-barrier tile loop.
__global__ __launch_bounds__(512) void fused_gemm_mfma_kernel(
    const short* __restrict__ accbf,     // [2V,128]
    const short* __restrict__ xbf,       // [V,128]
    const short* __restrict__ wpack,
    const float* __restrict__ bias,
    short* __restrict__ hbf,             // [V,128] bf16 intermediate
    float* __restrict__ stats_part,      // [NGB][256]
    int V, int NRB)
{
    __shared__ short wlds[3 * 4 * 4 * 64 * 8];   // 48 KB
    __shared__ float s_red[128];                 // [0:64] sum, [64:128] sumsq

    int tid  = threadIdx.x;
    int wave = tid >> 6;
    int lane = tid & 63;
    int kgrp = lane >> 4;
    int r16  = lane & 15;
    int bid  = blockIdx.x >> 1;
    int hh   = blockIdx.x & 1;

    if (tid < 128) s_red[tid] = 0.f;

    {
        const short8v* wsv = reinterpret_cast<const short8v*>(wpack);
        short8v* wldv = reinterpret_cast<short8v*>(wlds);
#pragma unroll
        for (int i = 0; i < 6; ++i) {
            int idx = i * 512 + tid;
            int l  = idx & 63;
            int t  = (idx >> 6) & 3;
            int cb = (idx >> 8) & 3;
            int m  = idx >> 10;
            wldv[idx] = wsv[(((size_t)m * 8 + (4 * hh + cb)) * 4 + t) * 64 + l];
        }
    }
    __syncthreads();   // weights staged; s_red zeroed. NO barriers after this.

    const short8v* wldv = reinterpret_cast<const short8v*>(wlds);
    float ps[4] = {0.f, 0.f, 0.f, 0.f};
    float pq[4] = {0.f, 0.f, 0.f, 0.f};

    for (int rt = bid; rt < NRB; rt += NGB) {
        int row0 = rt * 128 + wave * 16;
        int rowl = row0 + r16;
        int rowc = min(rowl, V - 1);

        short8v af[3][4];
        {
            const short* A0 = accbf + (size_t)rowc * 128;
            const short* A1 = accbf + (size_t)(V + rowc) * 128;
            const short* A2 = xbf + (size_t)rowc * 128;
#pragma unroll
            for (int t = 0; t < 4; ++t) {
                int o = t * 32 + (kgrp << 3);
                af[0][t] = *reinterpret_cast<const short8v*>(A0 + o);
                af[1][t] = *reinterpret_cast<const short8v*>(A1 + o);
                af[2][t] = *reinterpret_cast<const short8v*>(A2 + o);
            }
        }

        float4v c[4];
#pragma unroll
        for (int b = 0; b < 4; ++b) c[b] = (float4v)(0.f);

#pragma unroll
        for (int m = 0; m < 3; ++m)
#pragma unroll
            for (int t = 0; t < 4; ++t) {
#pragma unroll
                for (int b = 0; b < 4; ++b) {
                    short8v bf_ = wldv[(((m * 4 + b) * 4) + t) * 64 + lane];
                    c[b] = __builtin_amdgcn_mfma_f32_16x16x32_bf16(af[m][t], bf_, c[b], 0, 0, 0);
                }
            }

        // epilogue: C/D layout col=lane&15, row=(lane>>4)*4+r  [m89]
#pragma unroll
        for (int b = 0; b < 4; ++b) {
            int col = hh * 64 + b * 16 + r16;
            float bv = bias[col];
#pragma unroll
            for (int r = 0; r < 4; ++r) {
                int row = row0 + kgrp * 4 + r;
                if (row < V) {
                    float v = c[b][r] * (1.f / 3.f) + bv;
                    hbf[(size_t)row * 128 + col] = f2bf(v);
                    ps[b] += v;
                    pq[b] += v * v;
                }
            }
        }
    }

#pragma unroll
    for (int b = 0; b < 4; ++b) {
        int cl = b * 16 + r16;
        atomicAdd(&s_red[cl], ps[b]);
        atomicAdd(&s_red[64 + cl], pq[b]);
    }
    __syncthreads();
    if (tid < 64)
        stats_part[(size_t)bid * 256 + hh * 64 + tid] = s_red[tid];
    else if (tid < 128)
        stats_part[(size_t)bid * 256 + 128 + hh * 64 + (tid - 64)] = s_red[tid];
}

// BN reduce stage 1: 64 blocks, each sums a strided subset of NB partials
__global__ __launch_bounds__(256) void bn_reduce1_kernel(
    const float* __restrict__ stats_part, float* __restrict__ stage, int NB)
{
    int col = threadIdx.x;
    float s = 0.f;
    for (int i = blockIdx.x; i < NB; i += RED1)
        s += stats_part[(size_t)i * 256 + col];
    stage[(size_t)blockIdx.x * 256 + col] = s;
}

// fused: per-block stats finalize + BN apply + ReLU (bf16 in, f32 out);
// blocks >= NBA compute out_rel = rel @ w_rel.
__global__ __launch_bounds__(256) void bn_apply_fused_kernel(
    const short* __restrict__ hbf,
    float* __restrict__ hout,
    const float* __restrict__ stage,
    const float* __restrict__ gamma,
    const float* __restrict__ beta,
    int V, int NBA,
    const float* __restrict__ rel,
    const float* __restrict__ w_rel,
    float* __restrict__ out_rel,
    int R)
{
    int tid = threadIdx.x;
    if ((int)blockIdx.x >= NBA) {
        int rb = blockIdx.x - NBA;
        int col = tid & 127;
        int row = rb * 2 + (tid >> 7);
        if (row >= R) return;
        float acc = 0.f;
        for (int k = 0; k < 128; ++k)
            acc += rel[row * 128 + k] * w_rel[k * 128 + col];
        out_rel[row * 128 + col] = acc;
        return;
    }

    __shared__ float st[256];
    {
        float s0 = 0.f, s1 = 0.f, s2 = 0.f, s3 = 0.f;
#pragma unroll
        for (int i = 0; i < RED1; i += 4) {
            s0 += stage[(size_t)(i + 0) * 256 + tid];
            s1 += stage[(size_t)(i + 1) * 256 + tid];
            s2 += stage[(size_t)(i + 2) * 256 + tid];
            s3 += stage[(size_t)(i + 3) * 256 + tid];
        }
        st[tid] = (s0 + s1) + (s2 + s3);
    }
    __syncthreads();

    int c4   = (tid & 31) << 2;
    int rsub = tid >> 5;
    float inv_v = 1.f / (float)V;
    float sc[4], sh[4];
#pragma unroll
    for (int j = 0; j < 4; ++j) {
        int col = c4 + j;
        float mean = st[col] * inv_v;
        float var  = st[128 + col] * inv_v - mean * mean;
        float s = rsqrtf(var + 1e-5f) * gamma[col];
        sc[j] = s;
        sh[j] = beta[col] - mean * s;
    }
    for (int row = blockIdx.x * 8 + rsub; row < V; row += NBA * 8) {
        uint2 u = *reinterpret_cast<const uint2*>(hbf + (size_t)row * 128 + c4);
        float4 v;
        v.x = fmaxf(bflo(u.x) * sc[0] + sh[0], 0.f);
        v.y = fmaxf(bfhi(u.x) * sc[1] + sh[1], 0.f);
        v.z = fmaxf(bflo(u.y) * sc[2] + sh[2], 0.f);
        v.w = fmaxf(bfhi(u.y) * sc[3] + sh[3], 0.f);
        *reinterpret_cast<float4*>(hout + (size_t)row * 128 + c4) = v;
    }
}

extern "C" void kernel_launch(void* const* d_in, const int* in_sizes, int n_in,
                              void* d_out, int out_size, void* d_ws, size_t ws_size,
                              hipStream_t stream)
{
    const float* x         = (const float*)d_in[0];
    const float* rel_repr  = (const float*)d_in[1];
    const float* edge_norm = (const float*)d_in[2];
    const float* in_w      = (const float*)d_in[3];
    const float* out_w     = (const float*)d_in[4];
    const float* loop_w    = (const float*)d_in[5];
    const float* w_rel     = (const float*)d_in[6];
    const float* loop_rel  = (const float*)d_in[7];
    const float* bias      = (const float*)d_in[8];
    const float* bn_gamma  = (const float*)d_in[9];
    const float* bn_beta   = (const float*)d_in[10];
    const int* edge_type   = (const int*)d_in[11];
    const int* src         = (const int*)d_in[12];
    const int* dst         = (const int*)d_in[13];

    const int V = in_sizes[0] / 128;     // 50000
    const int E = in_sizes[2];           // 800000
    const int R = in_sizes[1] / 128;     // 200
    const int NK = 2 * V;                // keys: [dst(in) ; dst(out)]
    const int NBC = (NK + CB - 1) / CB;              // coarse buckets (782)
    const int NBLK = (E + CHUNK - 1) / CHUNK;        // hist/rank blocks (196)
    const int CN = NBC * NBLK;                       // scan length
    const int NB2 = (CN + SCAN_BLOCK - 1) / SCAN_BLOCK;
    const int NRB = (V + 127) / 128;                 // GEMM row tiles (391)
    const int NBA = 256;                             // bn_apply blocks
    const int XB  = (int)((((size_t)(V + R) * 128) / 8 + 255) / 256);  // xcast blocks

    float* hout    = (float*)d_out;              // [V,128]
    float* out_rel = hout + (size_t)V * 128;     // [R,128]

    // workspace layout
    char* wp_ = (char*)d_ws;
    short* accbf    = (short*)wp_;  wp_ += (size_t)NK * 128 * sizeof(short);
    short* xbf      = (short*)wp_;  wp_ += (size_t)V * 128 * sizeof(short);
    short* relbf    = (short*)wp_;  wp_ += (size_t)R * 128 * sizeof(short);
    short* hbf      = (short*)wp_;  wp_ += (size_t)V * 128 * sizeof(short);
    short* wpack    = (short*)wp_;  wp_ += (size_t)3 * 8 * 4 * 64 * 8 * sizeof(short);
    float* stats_pt = (float*)wp_;  wp_ += (size_t)NGB * 256 * sizeof(float);
    float* stage    = (float*)wp_;  wp_ += (size_t)RED1 * 256 * sizeof(float);
    int*   counts   = (int*)wp_;    wp_ += (size_t)CN * sizeof(int);   // block-major
    int*   basep    = (int*)wp_;    wp_ += (size_t)CN * sizeof(int);   // bucket-major
    int*   partials = (int*)wp_;    wp_ += 1024 * sizeof(int);
    int*   foffg    = (int*)wp_;    wp_ += ((size_t)NK + 2) * sizeof(int);
    wp_ = (char*)(((uintptr_t)wp_ + 15) & ~(uintptr_t)15);
    uint2* pay      = (uint2*)wp_;  wp_ += (size_t)E * sizeof(uint2);
    uint2* pay2     = (uint2*)wp_;

    // NOTE: no memset needed — every consumed workspace buffer is fully
    // written each call.

    prep_kernel<<<XB + 24 + NBLK, 256, 0, stream>>>(
        x, rel_repr, xbf, relbf,
        in_w, out_w, loop_w, loop_rel, wpack,
        dst, counts, V, R, E, NBC, XB);

    scan_partial_t_kernel<<<NB2, SCAN_BLOCK, 0, stream>>>(counts, partials, CN, NBC, NBLK);
    scan_final_t_kernel<<<NB2, SCAN_BLOCK, 0, stream>>>(counts, partials, basep, CN, NBC, NBLK);
    rank_coarse_kernel<<<NBLK, 512, 0, stream>>>(
        dst, src, edge_type, edge_norm, basep, pay, E, V, NBC, NBLK);
    fine_sort_kernel<<<NBC, 512, 0, stream>>>(
        pay, basep, pay2, foffg, E, NK, NBC, NBLK);

    {
        int waves = (NK + 3) / 4;                        // 25000
        int blocks = (waves * 64 + 255) / 256;           // 6250
        aggregate_g16_kernel<<<blocks, 256, 0, stream>>>(
            xbf, relbf, pay2, foffg, accbf, NK, E);
    }

    fused_gemm_mfma_kernel<<<NGB * 2, 512, 0, stream>>>(
        accbf, xbf, wpack, bias, hbf, stats_pt, V, NRB);

    bn_reduce1_kernel<<<RED1, 256, 0, stream>>>(stats_pt, stage, NGB);
    bn_apply_fused_kernel<<<NBA + (R + 1) / 2, 256, 0, stream>>>(
        hbf, hout, stage, bn_gamma, bn_beta, V, NBA,
        rel_repr, w_rel, out_rel, R);
}